// Round 8
// baseline (249.920 us; speedup 1.0000x reference)
//
#include <hip/hip_runtime.h>
#include <hip/hip_bf16.h>

#define ENS 7
#define SDIM 30
#define ADIM 8
#define DIN 38          // SDIM + ADIM
#define HID 200
#define DOUT 31         // SDIM + RDIM
#define NHL 3           // hidden layers
#define HS 232          // hA row stride in elems (116 words -> 2-way max on b128 reads)
#define MT 64           // rows per block

typedef __bf16 bf16x8 __attribute__((ext_vector_type(8)));
typedef float f32x4 __attribute__((ext_vector_type(4)));

// ws layout v3 (ushort elems): bf16 weights in WAVE-MAJOR fragment streams.
// Per (e, layer, wave w): a contiguous stream; frag (st, c) at (st*FPS + c)*512.
//   hidden-type layers (FPS=4): c=0..2 -> ct = 3w+c; c=3 -> shared ct 12 (DUPLICATED
//   into each wave's stream so every load is base + small imm).
//   head (FPS=1): ct = w, frag st at st*512.
// Fragment element (lane, j) = W[k = st*32 + (lane>>4)*8 + j][n = ct*16 + (lane&15)]
// (0 if OOB). Consumed as MFMA A operand (m = out-col).
#define ST_L1 (2 * 4 * 512)            // 4096   per-wave stream, layer 1 (S=2)
#define ST_H  (7 * 4 * 512)            // 14336  per-wave stream, hidden (S=7)
#define ST_HD (7 * 512)                // 3584   per-wave stream, head (S=7, FPS=1)
#define OFF_H0  (4 * ST_L1)            // 16384
#define OFF_HD3 (OFF_H0 + NHL * 4 * ST_H)   // 188416
#define PER_E   (OFF_HD3 + 4 * ST_HD)  // 202752
#define WS_TOTAL (ENS * PER_E)         // 1419264 ushorts = 2.84 MB

__device__ __forceinline__ unsigned short f2bf(float f) {
    unsigned u = __float_as_uint(f);
    u += 0x7fffu + ((u >> 16) & 1u);          // RNE
    return (unsigned short)(u >> 16);
}

__device__ __forceinline__ unsigned pk2(float a, float b) {
    __hip_bfloat162 h = __float22bfloat162_rn(make_float2(a, b));
    return *reinterpret_cast<unsigned*>(&h);
}

__device__ __forceinline__ float softplusf(float x) {
    return fmaxf(x, 0.f) + __logf(1.f + __expf(-fabsf(x)));
}

// ---- prep: fp32 weights -> bf16 wave-major fragment streams ----
__global__ void prep_kernel(const float* __restrict__ W1, const float* __restrict__ Wh,
                            const float* __restrict__ Wmu, const float* __restrict__ Wsig,
                            unsigned short* __restrict__ ws) {
    int idx = blockIdx.x * 256 + threadIdx.x;
    if (idx >= WS_TOTAL) return;
    int e = idx / PER_E, r = idx % PER_E;
    int j = r & 7, lane = (r >> 3) & 63;
    int l16 = lane & 15, q = lane >> 4;
    float v = 0.f;
    if (r < OFF_H0) {                          // layer 1 (S=2, FPS=4)
        int w = r / ST_L1, r2 = r % ST_L1;
        int fi = r2 >> 9;                      // st*4 + c
        int st = fi >> 2, c = fi & 3;
        int ct = (c < 3) ? (3 * w + c) : 12;
        int k = st * 32 + q * 8 + j, n = ct * 16 + l16;
        if (k < DIN && n < HID) v = W1[(e * DIN + k) * HID + n];
    } else if (r < OFF_HD3) {                  // hidden layers (S=7, FPS=4)
        int rh = r - OFF_H0;
        int l = rh / (4 * ST_H), r2 = rh % (4 * ST_H);
        int w = r2 / ST_H, r3 = r2 % ST_H;
        int fi = r3 >> 9;                      // st*4 + c
        int st = fi >> 2, c = fi & 3;
        int ct = (c < 3) ? (3 * w + c) : 12;
        int k = st * 32 + q * 8 + j, n = ct * 16 + l16;
        if (k < HID && n < HID) v = Wh[((l * ENS + e) * HID + (long)k) * HID + n];
    } else {                                   // head (S=7, FPS=1): ct = w
        int rh = r - OFF_HD3;
        int w = rh / ST_HD, r3 = rh % ST_HD;
        int st = r3 >> 9;
        int k = st * 32 + q * 8 + j, n = w * 16 + l16;
        if (k < HID) {
            if (n < DOUT) v = Wmu[(e * HID + k) * DOUT + n];
            else if (n >= 32 && n < 32 + DOUT) v = Wsig[(e * HID + k) * DOUT + (n - 32)];
        }
    }
    ws[idx] = f2bf(v);
}

// Hidden-type layer. b = this wave's stream (uniform base; per-load addr =
// base + (st*4+c)*1024B + lane*16B -> SALU/imm only). At the last K-step,
// prefetches the next layer's st=0 fragments (NFPS of them) into bq.
template<int S, int NFPS>
__device__ __forceinline__ void runHidden(const unsigned short* __restrict__ b,
                                          const unsigned short* __restrict__ nb,
                                          const unsigned short* hA,
                                          int lane, int swv, int l16, int quad,
                                          f32x4 (&accO)[4][3], f32x4& accS,
                                          bf16x8 (&bq)[4]) {
#pragma unroll
    for (int r = 0; r < 4; r++)
#pragma unroll
        for (int c = 0; c < 3; c++) accO[r][c] = (f32x4){0.f, 0.f, 0.f, 0.f};
    accS = (f32x4){0.f, 0.f, 0.f, 0.f};

#pragma unroll
    for (int st = 0; st < S; ++st) {
        bf16x8 bn[4];
        if (st + 1 < S) {
#pragma unroll
            for (int c = 0; c < 4; c++)
                bn[c] = *((const bf16x8*)(b + ((st + 1) * 4 + c) * 512 + lane * 8));
        } else {
#pragma unroll
            for (int c = 0; c < NFPS; c++)
                bn[c] = *((const bf16x8*)(nb + c * 512 + lane * 8));
        }
        bf16x8 af[4];
#pragma unroll
        for (int r = 0; r < 4; r++)
            af[r] = *((const bf16x8*)(hA + (r * 16 + l16) * HS + st * 32 + quad * 8));
        bf16x8 afs = *((const bf16x8*)(hA + (swv * 16 + l16) * HS + st * 32 + quad * 8));
#pragma unroll
        for (int c = 0; c < 3; c++)
#pragma unroll
            for (int r = 0; r < 4; r++)
                accO[r][c] = __builtin_amdgcn_mfma_f32_16x16x32_bf16(bq[c], af[r], accO[r][c], 0, 0, 0);
        accS = __builtin_amdgcn_mfma_f32_16x16x32_bf16(bq[3], afs, accS, 0, 0, 0);
        if (st + 1 < S) {
#pragma unroll
            for (int c = 0; c < 4; c++) bq[c] = bn[c];
        } else {
#pragma unroll
            for (int c = 0; c < NFPS; c++) bq[c] = bn[c];
        }
    }
}

// Head layer: 1 ct per wave (ct = swv), 4 row-tiles, FPS=1.
__device__ __forceinline__ void runHead(const unsigned short* __restrict__ b,
                                        const unsigned short* hA,
                                        int lane, int l16, int quad,
                                        f32x4 (&accO)[4][3], bf16x8& b0) {
#pragma unroll
    for (int r = 0; r < 4; r++) accO[r][0] = (f32x4){0.f, 0.f, 0.f, 0.f};
#pragma unroll
    for (int st = 0; st < 7; ++st) {
        bf16x8 bn;
        if (st + 1 < 7) bn = *((const bf16x8*)(b + (st + 1) * 512 + lane * 8));
        bf16x8 af[4];
#pragma unroll
        for (int r = 0; r < 4; r++)
            af[r] = *((const bf16x8*)(hA + (r * 16 + l16) * HS + st * 32 + quad * 8));
#pragma unroll
        for (int r = 0; r < 4; r++)
            accO[r][0] = __builtin_amdgcn_mfma_f32_16x16x32_bf16(b0, af[r], accO[r][0], 0, 0, 0);
        if (st + 1 < 7) b0 = bn;
    }
}

// ---- fused 5-layer ensemble MLP ----
// (256,3): R6 showed (256,4)'s 128-reg cap spills the accumulators.
__launch_bounds__(256, 3)
__global__ void ens_mlp_kernel(const float* __restrict__ s, const float* __restrict__ a,
                               const float* __restrict__ b1, const float* __restrict__ bh,
                               const float* __restrict__ bmu, const float* __restrict__ bsig,
                               const float* __restrict__ maxs, const float* __restrict__ mins,
                               const float* __restrict__ maxr, const float* __restrict__ minr,
                               const unsigned short* __restrict__ ws,
                               float* __restrict__ out, int N) {
    __shared__ unsigned short hA[MT * HS];     // 29696 B, activations (bf16) -- only LDS

    const int tid = threadIdx.x;
    const int wv = tid >> 6, lane = tid & 63;
    const int quad = lane >> 4, l16 = lane & 15;
    const int swv = __builtin_amdgcn_readfirstlane(wv);   // wave-uniform -> SGPR addressing
    const int bid = blockIdx.x;
    const int e = bid % ENS, n0 = (bid / ENS) * MT;

    // zero hA (K-pad cols must be 0; cols >=208 stay 0 forever)
    for (int i = tid; i < MT * HS / 8; i += 256) ((uint4*)hA)[i] = make_uint4(0, 0, 0, 0);
    __syncthreads();

    // stage x = concat(s, a) -> hA cols 0..37 (bf16)
    {
        int m = tid & 63, cg = tid >> 6;
        long g = n0 + m;
        const float* srow = s + (g * ENS + e) * SDIM;
        const float* arow = a + (g * ENS + e) * ADIM;
#pragma unroll
        for (int k = 0; k < 10; k++) {
            int c = cg * 10 + k;
            if (c < DIN) {
                float v = (c < SDIM) ? srow[c] : arow[c - SDIM];
                hA[m * HS + c] = f2bf(v);
            }
        }
    }
    __syncthreads();

    // wave-uniform stream bases
    const unsigned short* we  = ws + e * PER_E;
    const unsigned short* bL1 = we + swv * ST_L1;
    const unsigned short* bH0 = we + OFF_H0 + swv * ST_H;
    const unsigned short* bH1 = bH0 + 4 * ST_H;
    const unsigned short* bH2 = bH1 + 4 * ST_H;
    const unsigned short* bHD = we + OFF_HD3 + swv * ST_HD;

    f32x4 accO[4][3];   // own col-tiles: [row-tile][c], ct = 3*swv+c
    f32x4 accS;         // shared ct12, row-tile = swv
    bf16x8 bq[4];

    // bias + swish -> hA. Own cts: col < 192 always. Shared ct12: cols 192..207;
    // pad cols (>=200) have zero weights+bias -> writes swish(0)=0 = the K-pad zero.
    auto epiH = [&](const float* bias) {
#pragma unroll
        for (int c = 0; c < 3; c++) {
            int col = (3 * swv + c) * 16 + quad * 4;
            float4 bc4 = *((const float4*)(bias + col));
#pragma unroll
            for (int r = 0; r < 4; r++) {
                float v0 = accO[r][c][0] + bc4.x, v1 = accO[r][c][1] + bc4.y;
                float v2 = accO[r][c][2] + bc4.z, v3 = accO[r][c][3] + bc4.w;
                v0 *= __builtin_amdgcn_rcpf(1.f + __expf(-v0));
                v1 *= __builtin_amdgcn_rcpf(1.f + __expf(-v1));
                v2 *= __builtin_amdgcn_rcpf(1.f + __expf(-v2));
                v3 *= __builtin_amdgcn_rcpf(1.f + __expf(-v3));
                *((uint2*)(hA + (r * 16 + l16) * HS + col)) = make_uint2(pk2(v0, v1), pk2(v2, v3));
            }
        }
        {
            int col = 192 + quad * 4;
            float4 bc4 = make_float4(0.f, 0.f, 0.f, 0.f);
            if (col < HID) bc4 = *((const float4*)(bias + col));   // quad 0,1 only
            float v0 = accS[0] + bc4.x, v1 = accS[1] + bc4.y;
            float v2 = accS[2] + bc4.z, v3 = accS[3] + bc4.w;
            v0 *= __builtin_amdgcn_rcpf(1.f + __expf(-v0));
            v1 *= __builtin_amdgcn_rcpf(1.f + __expf(-v1));
            v2 *= __builtin_amdgcn_rcpf(1.f + __expf(-v2));
            v3 *= __builtin_amdgcn_rcpf(1.f + __expf(-v3));
            *((uint2*)(hA + (swv * 16 + l16) * HS + col)) = make_uint2(pk2(v0, v1), pk2(v2, v3));
        }
    };

    // preload L1 st=0 fragments
#pragma unroll
    for (int c = 0; c < 4; c++) bq[c] = *((const bf16x8*)(bL1 + c * 512 + lane * 8));

    runHidden<2, 4>(bL1, bH0, hA, lane, swv, l16, quad, accO, accS, bq);
    __syncthreads();
    epiH(b1 + e * HID);
    __syncthreads();
    runHidden<7, 4>(bH0, bH1, hA, lane, swv, l16, quad, accO, accS, bq);
    __syncthreads();
    epiH(bh + (0 * ENS + e) * HID);
    __syncthreads();
    runHidden<7, 4>(bH1, bH2, hA, lane, swv, l16, quad, accO, accS, bq);
    __syncthreads();
    epiH(bh + (1 * ENS + e) * HID);
    __syncthreads();
    runHidden<7, 1>(bH2, bHD, hA, lane, swv, l16, quad, accO, accS, bq);
    __syncthreads();
    epiH(bh + (2 * ENS + e) * HID);
    __syncthreads();
    runHead(bHD, hA, lane, l16, quad, accO, bq[0]);
    // no barrier: head tail reads only registers, writes only global

    // head tail: wave owns ct = swv -> lane holds cols swv*16+quad*4+{0..3}
    // (mu block 0..31 for swv<2, sigma block 32..63 for swv>=2), rows r*16+l16.
    const long off1 = (long)N * ENS * SDIM;    // ds_sg
    const long off2 = 2 * off1;                // r_mu
    const long off3 = off2 + (long)N * ENS;    // r_sg
    {
        const bool isSig = (swv >= 2);
        const int c0 = (swv & 1) * 16 + quad * 4;
        float bias_i[4], mx_i[4], mn_i[4];
#pragma unroll
        for (int i = 0; i < 4; i++) {
            int c = c0 + i;
            bias_i[i] = (c < DOUT) ? (isSig ? bsig : bmu)[e * DOUT + c] : 0.f;
            if (isSig) {
                mx_i[i] = (c < SDIM) ? maxs[c] : maxr[0];
                mn_i[i] = (c < SDIM) ? mins[c] : minr[0];
            }
        }
#pragma unroll
        for (int r = 0; r < 4; r++) {
            long g = n0 + r * 16 + l16;
            long rowbase = (g * ENS + e) * SDIM;
#pragma unroll
            for (int i = 0; i < 4; i++) {
                int c = c0 + i;
                if (c < DOUT) {
                    float v = accO[r][0][i] + bias_i[i];
                    if (!isSig) {
                        if (c < SDIM) out[rowbase + c] = v;
                        else out[off2 + g * ENS + e] = v;
                    } else {
                        v = 0.5f * (mx_i[i] - softplusf(mx_i[i] - 2.f * v));
                        v = 0.5f * (mn_i[i] + softplusf(2.f * v - mn_i[i]));
                        v = __expf(v);
                        if (c < SDIM) out[off1 + rowbase + c] = v;
                        else out[off3 + g * ENS + e] = v;
                    }
                }
            }
        }
    }
}

extern "C" void kernel_launch(void* const* d_in, const int* in_sizes, int n_in,
                              void* d_out, int out_size, void* d_ws, size_t ws_size,
                              hipStream_t stream) {
    const float* s    = (const float*)d_in[0];
    const float* a    = (const float*)d_in[1];
    const float* W1   = (const float*)d_in[2];
    const float* b1   = (const float*)d_in[3];
    const float* Wh   = (const float*)d_in[4];
    const float* bh   = (const float*)d_in[5];
    const float* Wmu  = (const float*)d_in[6];
    const float* bmu  = (const float*)d_in[7];
    const float* Wsig = (const float*)d_in[8];
    const float* bsig = (const float*)d_in[9];
    const float* maxs = (const float*)d_in[10];
    const float* mins = (const float*)d_in[11];
    const float* maxr = (const float*)d_in[12];
    const float* minr = (const float*)d_in[13];
    float* out = (float*)d_out;
    unsigned short* ws = (unsigned short*)d_ws;

    int N = in_sizes[0] / (ENS * SDIM);        // 32768

    int prepBlocks = (WS_TOTAL + 255) / 256;
    prep_kernel<<<prepBlocks, 256, 0, stream>>>(W1, Wh, Wmu, Wsig, ws);

    int mainBlocks = (N / MT) * ENS;           // 3584
    ens_mlp_kernel<<<mainBlocks, 256, 0, stream>>>(s, a, b1, bh, bmu, bsig,
                                                   maxs, mins, maxr, minr, ws, out, N);
}